// Round 1
// baseline (484.592 us; speedup 1.0000x reference)
//
#include <hip/hip_runtime.h>
#include <hip/hip_bf16.h>

typedef unsigned short u16;
typedef __attribute__((ext_vector_type(8))) short bf16x8;
typedef __attribute__((ext_vector_type(4))) float f32x4;

#define BTOK 4096
#define DDIM 1024
#define NEXP 8
#define HDIM 4096
#define ODIM 1024
#define MAXTILES 40
#define MAXROWS (MAXTILES * 128)  // 5120

__device__ __forceinline__ u16 f2bf(float f) {
  unsigned u = __float_as_uint(f);
  return (u16)((u + 0x7FFFu + ((u >> 16) & 1u)) >> 16);  // RNE
}

// ---------------- gating: one wave per token, fp64 accumulate ----------------
__global__ __launch_bounds__(256) void gate_kernel(
    const float* __restrict__ x, const float* __restrict__ Wg,
    const float* __restrict__ bg, int* __restrict__ assign,
    int* __restrict__ counts) {
  int wave = threadIdx.x >> 6;
  int lane = threadIdx.x & 63;
  int b = blockIdx.x * 4 + wave;
  const float* xr = x + (size_t)b * DDIM;
  double acc[NEXP];
#pragma unroll
  for (int e = 0; e < NEXP; ++e) acc[e] = 0.0;
  for (int d = lane; d < DDIM; d += 64) {
    float xv = xr[d];
    const float4* wrow = (const float4*)(Wg + d * NEXP);
    float4 w0 = wrow[0], w1 = wrow[1];
    acc[0] += (double)xv * (double)w0.x;
    acc[1] += (double)xv * (double)w0.y;
    acc[2] += (double)xv * (double)w0.z;
    acc[3] += (double)xv * (double)w0.w;
    acc[4] += (double)xv * (double)w1.x;
    acc[5] += (double)xv * (double)w1.y;
    acc[6] += (double)xv * (double)w1.z;
    acc[7] += (double)xv * (double)w1.w;
  }
#pragma unroll
  for (int e = 0; e < NEXP; ++e) {
    double v = acc[e];
#pragma unroll
    for (int off = 32; off > 0; off >>= 1) v += __shfl_xor(v, off);
    acc[e] = v;
  }
  if (lane == 0) {
    int best = 0;
    double bv = acc[0] + (double)bg[0];
#pragma unroll
    for (int e = 1; e < NEXP; ++e) {
      double v = acc[e] + (double)bg[e];
      if (v > bv) { bv = v; best = e; }  // first max wins (matches jnp.argmax)
    }
    assign[b] = best;
    atomicAdd(&counts[best], 1);
  }
}

// ---------------- setup: offsets, tile table, balance loss ----------------
__global__ void setup_kernel(const int* __restrict__ counts,
                             const float* __restrict__ wbal,
                             int* __restrict__ offp, int* __restrict__ tile_e,
                             int* __restrict__ tile_m, int* __restrict__ meta,
                             float* __restrict__ loss_out) {
  if (threadIdx.x != 0 || blockIdx.x != 0) return;
  int off = 0, nt = 0;
  for (int e = 0; e < NEXP; ++e) {
    offp[e] = off;
    int pc = (counts[e] + 127) & ~127;  // pad to 128
    for (int t = 0; t < (pc >> 7); ++t) {
      tile_e[nt] = e;
      tile_m[nt] = off + t * 128;
      ++nt;
    }
    off += pc;
  }
  offp[NEXP] = off;
  meta[0] = nt;
  float mean = (float)BTOK / (float)NEXP;
  float s = 0.f;
  for (int e = 0; e < NEXP; ++e) {
    float d = (float)counts[e] - mean;
    s += d * d;
  }
  loss_out[0] = s / (float)NEXP * wbal[0];
}

// ---------------- gather: token -> per-expert bucket, fp32 -> bf16 ----------------
__global__ __launch_bounds__(256) void gather_kernel(
    const float* __restrict__ x, const int* __restrict__ assign,
    const int* __restrict__ offp, int* __restrict__ fill,
    int* __restrict__ rowmap, u16* __restrict__ xg) {
  int b = blockIdx.x;
  __shared__ int srow;
  if (threadIdx.x == 0) {
    int e = assign[b];
    int pos = atomicAdd(&fill[e], 1);
    int row = offp[e] + pos;
    rowmap[row] = b;
    srow = row;
  }
  __syncthreads();
  int row = srow;
  float4 v = *(const float4*)(x + (size_t)b * DDIM + threadIdx.x * 4);
  ushort4 o;
  o.x = f2bf(v.x);
  o.y = f2bf(v.y);
  o.z = f2bf(v.z);
  o.w = f2bf(v.w);
  *(ushort4*)(xg + (size_t)row * DDIM + threadIdx.x * 4) = o;
}

// ---------------- grouped GEMM: [128 x 128] tile, BK=32, 4 waves ----------------
// LDS layout (A and B identical): row r (M-row for A, N-col for B), k-quad kq
// (8 bf16 = 16 B), swizzled: sq = kq ^ ((r&3) ^ ((r>>2)&3)), pitch 64 B.
// Both the b128 staging stores and b128 fragment reads are <=2-way conflicts.
template <int KDIM, int NDIM, bool FUSE_RELU>
__global__ __launch_bounds__(256, 2) void moe_gemm(
    const u16* __restrict__ A,      // bf16 [rows][KDIM]
    const float* __restrict__ W,    // fp32 [NEXP][KDIM][NDIM]
    const float* __restrict__ bias, // fp32 [NEXP][NDIM]
    const int* __restrict__ tile_e, const int* __restrict__ tile_m,
    const int* __restrict__ meta, const int* __restrict__ rowmap,
    u16* __restrict__ Hout,   // G1: bf16 [rows][NDIM]
    float* __restrict__ Cout) // G2: fp32 scatter [BTOK][NDIM]
{
  if ((int)blockIdx.x >= meta[0]) return;
  const int e = tile_e[blockIdx.x];
  const int m0 = tile_m[blockIdx.x];
  const int n0 = blockIdx.y * 128;

  __shared__ __align__(16) u16 Alds[128 * 32];
  __shared__ __align__(16) u16 Blds[128 * 32];

  const int tid = threadIdx.x;
  const int lane = tid & 63;
  const int wave = tid >> 6;
  const int wr = wave >> 1, wc = wave & 1;
  const int fr = lane & 15;
  const int kqr = lane >> 4;

  f32x4 acc[4][4];
#pragma unroll
  for (int i = 0; i < 4; ++i)
#pragma unroll
    for (int j = 0; j < 4; ++j)
#pragma unroll
      for (int r = 0; r < 4; ++r) acc[i][j][r] = 0.f;

  for (int kt = 0; kt < KDIM / 32; ++kt) {
// stage A: 128 rows x 32 k of bf16; thread loads 16 B contiguous
#pragma unroll
    for (int it = 0; it < 2; ++it) {
      int s = tid + it * 256;
      int row = s >> 2, kq = s & 3;
      const u16* src = A + (size_t)(m0 + row) * KDIM + kt * 32 + kq * 8;
      float4 v = *(const float4*)src;
      int sq = kq ^ ((row & 3) ^ ((row >> 2) & 3));
      *(float4*)&Alds[row * 32 + sq * 8] = v;
    }
// stage B: 32 k x 128 n fp32 -> transposed bf16; thread gathers a k-quad of
// one column (8 scalar loads, coalesced across lanes) -> one ds_write_b128
#pragma unroll
    for (int it = 0; it < 2; ++it) {
      int s = tid + it * 256;
      int c = s >> 2, kq = s & 3;
      const float* src =
          W + ((size_t)e * KDIM + (size_t)kt * 32 + kq * 8) * NDIM + n0 + c;
      u16 tmp[8];
#pragma unroll
      for (int i = 0; i < 8; ++i) tmp[i] = f2bf(src[(size_t)i * NDIM]);
      int sq = kq ^ ((c & 3) ^ ((c >> 2) & 3));
      *(float4*)&Blds[c * 32 + sq * 8] = *(float4*)tmp;
    }
    __syncthreads();
    bf16x8 af[4], bfr[4];
#pragma unroll
    for (int i = 0; i < 4; ++i) {
      int r = wr * 64 + i * 16 + fr;
      int sa = kqr ^ ((r & 3) ^ ((r >> 2) & 3));
      af[i] = *(const bf16x8*)&Alds[r * 32 + sa * 8];
      int c = wc * 64 + i * 16 + fr;
      int sb = kqr ^ ((c & 3) ^ ((c >> 2) & 3));
      bfr[i] = *(const bf16x8*)&Blds[c * 32 + sb * 8];
    }
#pragma unroll
    for (int i = 0; i < 4; ++i)
#pragma unroll
      for (int j = 0; j < 4; ++j)
        acc[i][j] =
            __builtin_amdgcn_mfma_f32_16x16x32_bf16(af[i], bfr[j], acc[i][j], 0, 0, 0);
    __syncthreads();
  }

  // epilogue: C/D layout col = lane&15, row = (lane>>4)*4 + reg
  if constexpr (FUSE_RELU) {
#pragma unroll
    for (int i = 0; i < 4; ++i) {
      int rbase = m0 + wr * 64 + i * 16 + (lane >> 4) * 4;
#pragma unroll
      for (int j = 0; j < 4; ++j) {
        int col = n0 + wc * 64 + j * 16 + fr;
        float bv = bias[e * NDIM + col];
#pragma unroll
        for (int r = 0; r < 4; ++r) {
          float v = acc[i][j][r] + bv;
          v = v > 0.f ? v : 0.f;
          Hout[(size_t)(rbase + r) * NDIM + col] = f2bf(v);
        }
      }
    }
  } else {
#pragma unroll
    for (int i = 0; i < 4; ++i) {
      int rbase = m0 + wr * 64 + i * 16 + (lane >> 4) * 4;
      int tok[4];
#pragma unroll
      for (int r = 0; r < 4; ++r) tok[r] = rowmap[rbase + r];
#pragma unroll
      for (int j = 0; j < 4; ++j) {
        int col = n0 + wc * 64 + j * 16 + fr;
        float bv = bias[e * NDIM + col];
#pragma unroll
        for (int r = 0; r < 4; ++r) {
          if (tok[r] >= 0) Cout[(size_t)tok[r] * NDIM + col] = acc[i][j][r] + bv;
        }
      }
    }
  }
}

extern "C" void kernel_launch(void* const* d_in, const int* in_sizes, int n_in,
                              void* d_out, int out_size, void* d_ws,
                              size_t ws_size, hipStream_t stream) {
  const float* x = (const float*)d_in[0];
  const float* Wg = (const float*)d_in[1];
  const float* bg = (const float*)d_in[2];
  const float* W1 = (const float*)d_in[3];
  const float* b1 = (const float*)d_in[4];
  const float* W2 = (const float*)d_in[5];
  const float* b2 = (const float*)d_in[6];
  const float* wbal = (const float*)d_in[7];
  float* out = (float*)d_out;

  char* ws = (char*)d_ws;
  int* counts = (int*)(ws + 0);
  int* fill = (int*)(ws + 64);
  int* offp = (int*)(ws + 128);
  int* meta = (int*)(ws + 192);
  int* tile_e = (int*)(ws + 256);
  int* tile_m = (int*)(ws + 512);
  int* assign = (int*)(ws + 4096);                       // 4096 ints
  int* rowmap = (int*)(ws + 4096 + BTOK * 4);            // MAXROWS ints
  u16* xg = (u16*)(ws + 65536);                          // MAXROWS x DDIM bf16
  u16* h = (u16*)(ws + 65536 + (size_t)MAXROWS * DDIM * 2);  // MAXROWS x HDIM bf16

  hipMemsetAsync(ws, 0, 4096, stream);                    // counts/fill/meta
  hipMemsetAsync(rowmap, 0xFF, MAXROWS * 4, stream);      // -1
  hipMemsetAsync(xg, 0, (size_t)MAXROWS * DDIM * 2, stream);  // zero pad rows

  gate_kernel<<<BTOK / 4, 256, 0, stream>>>(x, Wg, bg, assign, counts);
  setup_kernel<<<1, 64, 0, stream>>>(counts, wbal, offp, tile_e, tile_m, meta,
                                     out + (size_t)BTOK * ODIM);
  gather_kernel<<<BTOK, 256, 0, stream>>>(x, assign, offp, fill, rowmap, xg);

  moe_gemm<DDIM, HDIM, true><<<dim3(MAXTILES, HDIM / 128), 256, 0, stream>>>(
      xg, W1, b1, tile_e, tile_m, meta, rowmap, h, nullptr);
  moe_gemm<HDIM, ODIM, false><<<dim3(MAXTILES, ODIM / 128), 256, 0, stream>>>(
      h, W2, b2, tile_e, tile_m, meta, rowmap, nullptr, out);
}

// Round 2
// 367.351 us; speedup vs baseline: 1.3192x; 1.3192x over previous
//
#include <hip/hip_runtime.h>
#include <hip/hip_bf16.h>

typedef unsigned short u16;
typedef __attribute__((ext_vector_type(8))) short bf16x8;
typedef __attribute__((ext_vector_type(4))) float f32x4;

#define BTOK 4096
#define DDIM 1024
#define NEXP 8
#define HDIM 4096
#define ODIM 1024
#define MAXTILES 40
#define MAXROWS (MAXTILES * 128)  // 5120

__device__ __forceinline__ u16 f2bf(float f) {
  unsigned u = __float_as_uint(f);
  return (u16)((u + 0x7FFFu + ((u >> 16) & 1u)) >> 16);  // RNE
}

__device__ __forceinline__ void gload16(const void* g, void* l) {
  __builtin_amdgcn_global_load_lds(
      (const __attribute__((address_space(1))) void*)g,
      (__attribute__((address_space(3))) void*)l, 16, 0, 0);
}

// ---------------- gating: one wave per token, fp64 accumulate ----------------
__global__ __launch_bounds__(256) void gate_kernel(
    const float* __restrict__ x, const float* __restrict__ Wg,
    const float* __restrict__ bg, int* __restrict__ assign,
    int* __restrict__ counts) {
  int wave = threadIdx.x >> 6;
  int lane = threadIdx.x & 63;
  int b = blockIdx.x * 4 + wave;
  const float* xr = x + (size_t)b * DDIM;
  double acc[NEXP];
#pragma unroll
  for (int e = 0; e < NEXP; ++e) acc[e] = 0.0;
  for (int d = lane; d < DDIM; d += 64) {
    float xv = xr[d];
    const float4* wrow = (const float4*)(Wg + d * NEXP);
    float4 w0 = wrow[0], w1 = wrow[1];
    acc[0] += (double)xv * (double)w0.x;
    acc[1] += (double)xv * (double)w0.y;
    acc[2] += (double)xv * (double)w0.z;
    acc[3] += (double)xv * (double)w0.w;
    acc[4] += (double)xv * (double)w1.x;
    acc[5] += (double)xv * (double)w1.y;
    acc[6] += (double)xv * (double)w1.z;
    acc[7] += (double)xv * (double)w1.w;
  }
#pragma unroll
  for (int e = 0; e < NEXP; ++e) {
    double v = acc[e];
#pragma unroll
    for (int off = 32; off > 0; off >>= 1) v += __shfl_xor(v, off);
    acc[e] = v;
  }
  if (lane == 0) {
    int best = 0;
    double bv = acc[0] + (double)bg[0];
#pragma unroll
    for (int e = 1; e < NEXP; ++e) {
      double v = acc[e] + (double)bg[e];
      if (v > bv) { bv = v; best = e; }  // first max wins (matches jnp.argmax)
    }
    assign[b] = best;
    atomicAdd(&counts[best], 1);
  }
}

// ---------------- setup: offsets, tile table, balance loss ----------------
__global__ void setup_kernel(const int* __restrict__ counts,
                             const float* __restrict__ wbal,
                             int* __restrict__ offp, int* __restrict__ tile_e,
                             int* __restrict__ tile_m, int* __restrict__ meta,
                             float* __restrict__ loss_out) {
  if (threadIdx.x != 0 || blockIdx.x != 0) return;
  int off = 0, nt = 0;
  for (int e = 0; e < NEXP; ++e) {
    offp[e] = off;
    int pc = (counts[e] + 127) & ~127;  // pad to 128
    for (int t = 0; t < (pc >> 7); ++t) {
      tile_e[nt] = e;
      tile_m[nt] = off + t * 128;
      ++nt;
    }
    off += pc;
  }
  offp[NEXP] = off;
  meta[0] = nt;
  float mean = (float)BTOK / (float)NEXP;
  float s = 0.f;
  for (int e = 0; e < NEXP; ++e) {
    float d = (float)counts[e] - mean;
    s += d * d;
  }
  loss_out[0] = s / (float)NEXP * wbal[0];
}

// ---------------- gather: token -> per-expert bucket, fp32 -> bf16 ----------------
__global__ __launch_bounds__(256) void gather_kernel(
    const float* __restrict__ x, const int* __restrict__ assign,
    const int* __restrict__ offp, int* __restrict__ fill,
    int* __restrict__ rowmap, u16* __restrict__ xg) {
  int b = blockIdx.x;
  __shared__ int srow;
  if (threadIdx.x == 0) {
    int e = assign[b];
    int pos = atomicAdd(&fill[e], 1);
    int row = offp[e] + pos;
    rowmap[row] = b;
    srow = row;
  }
  __syncthreads();
  int row = srow;
  float4 v = *(const float4*)(x + (size_t)b * DDIM + threadIdx.x * 4);
  ushort4 o;
  o.x = f2bf(v.x);
  o.y = f2bf(v.y);
  o.z = f2bf(v.z);
  o.w = f2bf(v.w);
  *(ushort4*)(xg + (size_t)row * DDIM + threadIdx.x * 4) = o;
}

// ---------------- transpose+convert: fp32 [K][N] slice -> bf16 [NC][KR] ----------
// One 64x64 tile per block. Read coalesced along N, write coalesced along K.
__global__ __launch_bounds__(256) void transpose_conv(
    const float* __restrict__ W, u16* __restrict__ wt, int inN,
    size_t estrideIn, int k0, int n0, int KR, int NC) {
  const int e = blockIdx.z;
  const int kb = blockIdx.x * 64, nb = blockIdx.y * 64;
  __shared__ float lds[64][68];
  const float* src = W + (size_t)e * estrideIn + (size_t)k0 * inN + n0;
  const int t = threadIdx.x;
  const int rr = t >> 4, cc = (t & 15) * 4;
#pragma unroll
  for (int p = 0; p < 4; ++p) {
    float4 v = *(const float4*)(src + (size_t)(kb + rr + p * 16) * inN + nb + cc);
    *(float4*)&lds[rr + p * 16][cc] = v;
  }
  __syncthreads();
  const int n = t >> 2, kg = (t & 3) * 16;
  u16 tmp[16];
#pragma unroll
  for (int i = 0; i < 16; ++i) tmp[i] = f2bf(lds[kg + i][n]);
  u16* dst = wt + ((size_t)e * NC + nb + n) * KR + kb + kg;
  *(float4*)dst = *(float4*)&tmp[0];
  *(float4*)(dst + 8) = *(float4*)&tmp[8];
}

// ---------------- grouped GEMM, m97 structure + XOR swizzle ----------------
// Tile 128x128, BK=32, 4 waves (2x2), mfma_f32_16x16x32_bf16, acc 4x4.
// LDS unit u (16B) holds (row = u>>2, kq = (u&3) ^ (row&3)) -> linear
// global_load_lds dest + inverse-swizzled global source + swizzled ds_read:
// fragment b128 reads are exactly 2-way bank aliased (free).
// MODE 0: Hout = relu(acc + b1)  (bf16, chunk-local cols, ldh stride)
// MODE 1: Cout[tok] = acc + b2   (fp32 scatter)
// MODE 2: Cout[tok] += acc       (fp32 RMW accumulate, later K-chunks)
template <int K, int MODE>
__global__ __launch_bounds__(256) void moe_gemm(
    const u16* __restrict__ A, const u16* __restrict__ BT,
    const float* __restrict__ bias, const int* __restrict__ tile_e,
    const int* __restrict__ tile_m, const int* __restrict__ meta,
    const int* __restrict__ rowmap, u16* __restrict__ Hout,
    float* __restrict__ Cout, int NB, int ldh, int cOff, int biasLd) {
  if ((int)blockIdx.x >= meta[0]) return;
  const int e = tile_e[blockIdx.x];
  const int m0 = tile_m[blockIdx.x];
  const int n0 = blockIdx.y * 128;

  __shared__ __align__(16) u16 Alds[128 * 32];
  __shared__ __align__(16) u16 Blds[128 * 32];

  const int tid = threadIdx.x;
  const int lane = tid & 63;
  const int wave = tid >> 6;
  const int wr = wave >> 1, wc = wave & 1;
  const int fr = lane & 15;
  const int kqr = lane >> 4;

  // staging: unit u = it*256 + tid; source element for that linear LDS slot
  const int u1 = tid + 256;
  const int rA0 = tid >> 2, kA0 = (tid & 3) ^ (rA0 & 3);
  const int rA1 = u1 >> 2, kA1 = (u1 & 3) ^ (rA1 & 3);
  const u16* aSrc0 = A + (size_t)(m0 + rA0) * K + kA0 * 8;
  const u16* aSrc1 = A + (size_t)(m0 + rA1) * K + kA1 * 8;
  const u16* bPan = BT + ((size_t)e * NB + n0) * K;
  const u16* bSrc0 = bPan + (size_t)rA0 * K + kA0 * 8;
  const u16* bSrc1 = bPan + (size_t)rA1 * K + kA1 * 8;
  u16* aDst0 = Alds + (size_t)(tid & ~63) * 8;
  u16* aDst1 = Alds + ((size_t)(tid & ~63) + 256) * 8;
  u16* bDst0 = Blds + (size_t)(tid & ~63) * 8;
  u16* bDst1 = Blds + ((size_t)(tid & ~63) + 256) * 8;

  // constant fragment offsets (swizzled)
  int aOff[4], bOff[4];
#pragma unroll
  for (int i = 0; i < 4; ++i) {
    int r = wr * 64 + i * 16 + fr;
    aOff[i] = (r * 4 + (kqr ^ (r & 3))) * 8;
    int c = wc * 64 + i * 16 + fr;
    bOff[i] = (c * 4 + (kqr ^ (c & 3))) * 8;
  }

  f32x4 acc[4][4];
#pragma unroll
  for (int i = 0; i < 4; ++i)
#pragma unroll
    for (int j = 0; j < 4; ++j)
#pragma unroll
      for (int r = 0; r < 4; ++r) acc[i][j][r] = 0.f;

#pragma unroll 1
  for (int kt = 0; kt < K / 32; ++kt) {
    const int ko = kt * 32;
    gload16(aSrc0 + ko, aDst0);
    gload16(aSrc1 + ko, aDst1);
    gload16(bSrc0 + ko, bDst0);
    gload16(bSrc1 + ko, bDst1);
    __syncthreads();  // compiler drains vmcnt before barrier
    bf16x8 af[4], bfr[4];
#pragma unroll
    for (int i = 0; i < 4; ++i) {
      af[i] = *(const bf16x8*)&Alds[aOff[i]];
      bfr[i] = *(const bf16x8*)&Blds[bOff[i]];
    }
#pragma unroll
    for (int i = 0; i < 4; ++i)
#pragma unroll
      for (int j = 0; j < 4; ++j)
        acc[i][j] = __builtin_amdgcn_mfma_f32_16x16x32_bf16(af[i], bfr[j],
                                                            acc[i][j], 0, 0, 0);
    __syncthreads();
  }

  // epilogue: C/D layout col = lane&15, row = (lane>>4)*4 + reg
  if constexpr (MODE == 0) {
#pragma unroll
    for (int i = 0; i < 4; ++i) {
      int rbase = m0 + wr * 64 + i * 16 + (lane >> 4) * 4;
#pragma unroll
      for (int j = 0; j < 4; ++j) {
        int col = n0 + wc * 64 + j * 16 + fr;
        float bv = bias[e * biasLd + cOff + col];
#pragma unroll
        for (int r = 0; r < 4; ++r) {
          float v = acc[i][j][r] + bv;
          v = v > 0.f ? v : 0.f;
          Hout[(size_t)(rbase + r) * ldh + col] = f2bf(v);
        }
      }
    }
  } else {
#pragma unroll
    for (int i = 0; i < 4; ++i) {
      int rbase = m0 + wr * 64 + i * 16 + (lane >> 4) * 4;
      int tok[4];
#pragma unroll
      for (int r = 0; r < 4; ++r) tok[r] = rowmap[rbase + r];
#pragma unroll
      for (int j = 0; j < 4; ++j) {
        int col = n0 + wc * 64 + j * 16 + fr;
        float bv = (MODE == 1) ? bias[e * biasLd + col] : 0.f;
#pragma unroll
        for (int r = 0; r < 4; ++r) {
          if (tok[r] >= 0) {
            size_t idx = (size_t)tok[r] * ODIM + col;
            if constexpr (MODE == 1)
              Cout[idx] = acc[i][j][r] + bv;
            else
              Cout[idx] += acc[i][j][r];
          }
        }
      }
    }
  }
}

// ---------------- host-side chunked pipeline ----------------
template <int HC>
static void run_pipeline(const float* W1, const float* b1, const float* W2,
                         const float* b2, const u16* xg, u16* h, u16* wt,
                         const int* tile_e, const int* tile_m, const int* meta,
                         const int* rowmap, float* out, hipStream_t stream) {
  constexpr int NCH = HDIM / HC;
  for (int c = 0; c < NCH; ++c) {
    // W1 cols [c*HC, c*HC+HC) -> wt [E][HC][DDIM]
    transpose_conv<<<dim3(DDIM / 64, HC / 64, NEXP), 256, 0, stream>>>(
        W1, wt, HDIM, (size_t)DDIM * HDIM, 0, c * HC, DDIM, HC);
    moe_gemm<DDIM, 0><<<dim3(MAXTILES, HC / 128), 256, 0, stream>>>(
        xg, wt, b1, tile_e, tile_m, meta, rowmap, h, nullptr, HC, HC, c * HC,
        HDIM);
    // W2 rows [c*HC, c*HC+HC) -> wt [E][ODIM][HC]
    transpose_conv<<<dim3(HC / 64, ODIM / 64, NEXP), 256, 0, stream>>>(
        W2, wt, ODIM, (size_t)HDIM * ODIM, c * HC, 0, HC, ODIM);
    if (c == 0)
      moe_gemm<HC, 1><<<dim3(MAXTILES, ODIM / 128), 256, 0, stream>>>(
          h, wt, b2, tile_e, tile_m, meta, rowmap, nullptr, out, ODIM, 0, 0,
          ODIM);
    else
      moe_gemm<HC, 2><<<dim3(MAXTILES, ODIM / 128), 256, 0, stream>>>(
          h, wt, b2, tile_e, tile_m, meta, rowmap, nullptr, out, ODIM, 0, 0,
          ODIM);
  }
}

extern "C" void kernel_launch(void* const* d_in, const int* in_sizes, int n_in,
                              void* d_out, int out_size, void* d_ws,
                              size_t ws_size, hipStream_t stream) {
  const float* x = (const float*)d_in[0];
  const float* Wg = (const float*)d_in[1];
  const float* bg = (const float*)d_in[2];
  const float* W1 = (const float*)d_in[3];
  const float* b1 = (const float*)d_in[4];
  const float* W2 = (const float*)d_in[5];
  const float* b2 = (const float*)d_in[6];
  const float* wbal = (const float*)d_in[7];
  float* out = (float*)d_out;

  char* ws = (char*)d_ws;
  int* counts = (int*)(ws + 0);
  int* fill = (int*)(ws + 64);
  int* offp = (int*)(ws + 128);
  int* meta = (int*)(ws + 192);
  int* tile_e = (int*)(ws + 256);
  int* tile_m = (int*)(ws + 512);
  int* assign = (int*)(ws + 4096);
  int* rowmap = (int*)(ws + 4096 + BTOK * 4);
  u16* xg = (u16*)(ws + 65536);                              // MAXROWS x DDIM
  u16* h = (u16*)(ws + 65536 + (size_t)MAXROWS * DDIM * 2);  // MAXROWS x HC

  // pick largest H-chunk that fits ws: need = 65536 + xg + h(HC) + wt(HC)
  const size_t base = 65536 + (size_t)MAXROWS * DDIM * 2;
  auto need = [&](int hc) {
    return base + (size_t)MAXROWS * hc * 2 + (size_t)NEXP * 1024 * hc * 2;
  };

  hipMemsetAsync(ws, 0, 4096, stream);
  hipMemsetAsync(rowmap, 0xFF, MAXROWS * 4, stream);
  hipMemsetAsync(xg, 0, (size_t)MAXROWS * DDIM * 2, stream);

  gate_kernel<<<BTOK / 4, 256, 0, stream>>>(x, Wg, bg, assign, counts);
  setup_kernel<<<1, 64, 0, stream>>>(counts, wbal, offp, tile_e, tile_m, meta,
                                     out + (size_t)BTOK * ODIM);
  gather_kernel<<<BTOK, 256, 0, stream>>>(x, assign, offp, fill, rowmap, xg);

  if (ws_size >= need(4096)) {
    u16* wt = (u16*)(ws + base + (size_t)MAXROWS * 4096 * 2);
    run_pipeline<4096>(W1, b1, W2, b2, xg, (u16*)(ws + base), wt, tile_e,
                       tile_m, meta, rowmap, out, stream);
  } else if (ws_size >= need(2048)) {
    u16* wt = (u16*)(ws + base + (size_t)MAXROWS * 2048 * 2);
    run_pipeline<2048>(W1, b1, W2, b2, xg, (u16*)(ws + base), wt, tile_e,
                       tile_m, meta, rowmap, out, stream);
  } else if (ws_size >= need(1024)) {
    u16* wt = (u16*)(ws + base + (size_t)MAXROWS * 1024 * 2);
    run_pipeline<1024>(W1, b1, W2, b2, xg, (u16*)(ws + base), wt, tile_e,
                       tile_m, meta, rowmap, out, stream);
  } else {
    u16* wt = (u16*)(ws + base + (size_t)MAXROWS * 512 * 2);
    run_pipeline<512>(W1, b1, W2, b2, xg, (u16*)(ws + base), wt, tile_e,
                      tile_m, meta, rowmap, out, stream);
  }
}